// Round 11
// baseline (141.656 us; speedup 1.0000x reference)
//
#include <hip/hip_runtime.h>

// SimpleCRFHead R16: R15 (dual-chain ILP fusion) with the bwd path-index
// bug fixed. ONE wave per 16 sequences runs BOTH fwd (t=0..127) and bwd
// (t=255..128) recursions interleaved F,B,F,B -- two independent chains
// fill each other's FMA/DPP/exp latency. 512 blocks x 64 threads. Both
// partials end in-wave -> score computed in-registers (quad butterfly dot,
// log2, path-score), written straight to out (no ws, no combine kernel).
// FIX vs R15: PREREAD_B reads plr[254-TBN-kk] (p_{t-1} with full-row
// staging, clamp 127), was plr[127-TBN-kk] (off by 127 -> absmax 64).
// Per-direction math identical to R13 (absmax 0.0).

#define B_N 8192
#define L_N 256
#define SEQ_STRIDE 2304      // L_N * 9
#define HALF 128
#define SPB 6                // steps per x window
#define XW 54                // floats per seq per window
#define XSTRIDE 55           // odd -> conflict-free LDS banks
#define PLS 257              // full path row stride (odd)
#define SPW 16               // seqs per wave
#define NBLOCKS (B_N / SPW)  // 512

#define LOG2E 1.44269504088896340736f
#define LN2f  0.69314718055994530942f

#define QP1 57    // perm(1,2,3,0)
#define QP2 78    // perm(2,3,0,1)
#define QP3 147   // perm(3,0,1,2)
#define QPX1 177  // perm(1,0,3,2)  xor1 butterfly
#define QROT(src, CTRL) \
  __int_as_float(__builtin_amdgcn_mov_dpp(__float_as_int(src), CTRL, 0xf, 0xf, 0))

#define WAITV0 asm volatile("s_waitcnt vmcnt(0)" ::: "memory")

__device__ __forceinline__ void gl_lds4(const void* g, void* l) {
  __builtin_amdgcn_global_load_lds(
      (const __attribute__((address_space(1))) void*)g,
      (__attribute__((address_space(3))) void*)l, 4, 0, 0);
}

__device__ __forceinline__ float fexp(float x) {
  return __builtin_amdgcn_exp2f(x * LOG2E);   // v_exp_f32 = 2^x
}

#define FSTEP(KK, DO_RESC)                                                  \
  do {                                                                      \
    float g[4][3];                                                          \
    _Pragma("unroll") for (int k = 0; k < 3; ++k) {                         \
      g[0][k] = of[k];                                                      \
      g[1][k] = QROT(of[k], QP1);                                           \
      g[2][k] = QROT(of[k], QP2);                                           \
      g[3][k] = QROT(of[k], QP3);                                           \
    }                                                                       \
    if (DO_RESC) {                                                          \
      float m = g[0][0];                                                    \
      _Pragma("unroll") for (int r = 0; r < 4; ++r)                         \
        _Pragma("unroll") for (int k = 0; k < 3; ++k)                       \
          m = fmaxf(m, g[r][k]);                                            \
      const int ex = (int)((__float_as_uint(m) >> 23) & 0xffu) - 126;       \
      ce_f += ex;                                                           \
      const float sc = __uint_as_float((unsigned)(127 - ex) << 23);         \
      _Pragma("unroll") for (int r = 0; r < 4; ++r)                         \
        _Pragma("unroll") for (int k = 0; k < 3; ++k)                       \
          g[r][k] *= sc;                                                    \
    }                                                                       \
    float out3[3];                                                          \
    _Pragma("unroll") for (int i = 0; i < 3; ++i) {                         \
      float a = Erf[0][0][i] * g[0][0];                                     \
      _Pragma("unroll") for (int r = 0; r < 4; ++r)                         \
        _Pragma("unroll") for (int k = 0; k < 3; ++k)                       \
          if (r + k > 0) a = fmaf(Erf[r][k][i], g[r][k], a);                \
      out3[i] = a;                                                          \
    }                                                                       \
    _Pragma("unroll") for (int i = 0; i < 3; ++i)                           \
      of[i] = out3[i] * eCf[(KK) * 3 + i];                                  \
  } while (0)

#define BSTEP(KK, DO_RESC)                                                  \
  do {                                                                      \
    const int tt_ = 5 - (KK);                                               \
    float wv[3];                                                            \
    _Pragma("unroll") for (int k = 0; k < 3; ++k)                           \
      wv[k] = eCb[tt_ * 3 + k] * ob[k];                                     \
    float g[4][3];                                                          \
    _Pragma("unroll") for (int k = 0; k < 3; ++k) {                         \
      g[0][k] = wv[k];                                                      \
      g[1][k] = QROT(wv[k], QP1);                                           \
      g[2][k] = QROT(wv[k], QP2);                                           \
      g[3][k] = QROT(wv[k], QP3);                                           \
    }                                                                       \
    if (DO_RESC) {                                                          \
      float m = g[0][0];                                                    \
      _Pragma("unroll") for (int r = 0; r < 4; ++r)                         \
        _Pragma("unroll") for (int k = 0; k < 3; ++k)                       \
          m = fmaxf(m, g[r][k]);                                            \
      const int ex = (int)((__float_as_uint(m) >> 23) & 0xffu) - 126;       \
      ce_b += ex;                                                           \
      const float sc = __uint_as_float((unsigned)(127 - ex) << 23);         \
      _Pragma("unroll") for (int r = 0; r < 4; ++r)                         \
        _Pragma("unroll") for (int k = 0; k < 3; ++k)                       \
          g[r][k] *= sc;                                                    \
    }                                                                       \
    float out3[3];                                                          \
    _Pragma("unroll") for (int i = 0; i < 3; ++i) {                         \
      float a = Erb[0][0][i] * g[0][0];                                     \
      _Pragma("unroll") for (int r = 0; r < 4; ++r)                         \
        _Pragma("unroll") for (int k = 0; k < 3; ++k)                       \
          if (r + k > 0) a = fmaf(Erb[r][k][i], g[r][k], a);                \
      out3[i] = a;                                                          \
    }                                                                       \
    _Pragma("unroll") for (int i = 0; i < 3; ++i) ob[i] = out3[i];          \
  } while (0)

#define PREFETCH_F(NB)                                                      \
  if (lane < XW) {                                                          \
    const int fb = (NB) * XW;                                               \
    float* dst = &lxf[(NB) & 1][0];                                         \
    _Pragma("unroll") for (int r = 0; r < SPW; ++r)                         \
      gl_lds4(xg + (size_t)(seq0 + r) * SEQ_STRIDE + fb + lane,             \
              dst + r * XSTRIDE);                                           \
  }
#define PREFETCH_B(NB)                                                      \
  if (lane < XW) {                                                          \
    const int fb = SEQ_STRIDE - XW * ((NB) + 1);                            \
    float* dst = &lxb[(NB) & 1][0];                                         \
    _Pragma("unroll") for (int r = 0; r < SPW; ++r)                         \
      gl_lds4(xg + (size_t)(seq0 + r) * SEQ_STRIDE + fb + lane,             \
              dst + r * XSTRIDE);                                           \
  }

#define EBATCH_TO(EA, LXQ)                                                  \
  _Pragma("unroll") for (int tt = 0; tt < 6; ++tt)                          \
    _Pragma("unroll") for (int k = 0; k < 3; ++k)                           \
      EA[tt * 3 + k] = fexp((LXQ)[tt * 9 + myoff + k]);

#define EMTR_F(EMA, TRA, LXQ, PCA, PPREV)                                   \
  _Pragma("unroll") for (int kk = 0; kk < 6; ++kk) {                        \
    EMA[kk] = (LXQ)[kk * 9 + PCA[kk]];                                      \
    const int pp_ = kk ? PCA[kk - 1] : (PPREV);                             \
    TRA[kk] = ltran[pp_ * 9 + PCA[kk]];                                     \
  }
#define EMTR_B(EMA, TRA, LXQ, PCA, PPREV)                                   \
  _Pragma("unroll") for (int kk = 0; kk < 6; ++kk) {                        \
    const int pc_ = kk ? PCA[kk - 1] : (PPREV);                             \
    EMA[kk] = (LXQ)[(5 - kk) * 9 + pc_];                                    \
    TRA[kk] = ltran[PCA[kk] * 9 + pc_];                                     \
  }

#define PREREAD_F(PNA, TBN)                                                 \
  _Pragma("unroll") for (int kk = 0; kk < 6; ++kk) {                        \
    int t_ = (TBN) + kk; if (t_ > HALF - 1) t_ = HALF - 1;                  \
    PNA[kk] = plr[t_];                                                      \
  }
// p_{t-1} for t = 255-TBN-kk with FULL-row staging: index 254-TBN-kk.
// Clamp at 127 (minimum legitimate t-1; lower slots are unused tail).
#define PREREAD_B(PNA, TBN)                                                 \
  _Pragma("unroll") for (int kk = 0; kk < 6; ++kk) {                        \
    int idx_ = 254 - (TBN) - kk; if (idx_ < 127) idx_ = 127;                \
    PNA[kk] = plr[idx_];                                                    \
  }

__global__ __launch_bounds__(64, 1) void crf_fused(
    const float* __restrict__ xg, const int* __restrict__ path,
    const float* __restrict__ tran, const float* __restrict__ initv,
    float* __restrict__ out)
{
  __shared__ float lxf[2][SPW * XSTRIDE];  // 7040 B
  __shared__ float lxb[2][SPW * XSTRIDE];  // 7040 B
  __shared__ int   pl[SPW * PLS];          // 16448 B (full 256-step rows)
  __shared__ float ltran[81];              // ~31 KB -> 2 blocks/CU ok

  const int lane = threadIdx.x;
  const int c = lane & 3;
  const int q = lane >> 2;
  const int seq0 = blockIdx.x * SPW;

  for (int i = lane; i < 81; i += 64) ltran[i] = tran[i];

#pragma unroll
  for (int r = 0; r < SPW; ++r) {
    const int* g = path + (size_t)(seq0 + r) * L_N + lane;
    gl_lds4(g,       &pl[r * PLS]);
    gl_lds4(g + 64,  &pl[r * PLS + 64]);
    gl_lds4(g + 128, &pl[r * PLS + 128]);
    gl_lds4(g + 192, &pl[r * PLS + 192]);
  }
  if (lane < XW) {
#pragma unroll
    for (int r = 0; r < SPW; ++r) {
      gl_lds4(xg + (size_t)(seq0 + r) * SEQ_STRIDE + lane,
              &lxf[0][r * XSTRIDE]);
      gl_lds4(xg + (size_t)(seq0 + r) * SEQ_STRIDE + (SEQ_STRIDE - XW) + lane,
              &lxb[0][r * XSTRIDE]);
    }
  }

  float Erf[4][3][3], Erb[4][3][3];
#pragma unroll
  for (int r = 0; r < 4; ++r)
#pragma unroll
    for (int k = 0; k < 3; ++k)
#pragma unroll
      for (int i = 0; i < 3; ++i) {
        const int ig = 3 * c + i;
        const int jg = 3 * ((c + r) & 3) + k;
        float vf = 0.f, vb = 0.f;
        if (ig < 9 && jg < 9) {
          vf = fexp(tran[jg * 9 + ig]);
          vb = fexp(tran[ig * 9 + jg]);
        }
        Erf[r][k][i] = vf;
        Erb[r][k][i] = vb;
      }

  float iv[3];
#pragma unroll
  for (int k = 0; k < 3; ++k) {
    iv[k] = (c < 3) ? initv[3 * c + k] : 0.f;
    asm volatile("" :: "v"(iv[k]));
  }

  float of[3], ob[3];
#pragma unroll
  for (int k = 0; k < 3; ++k) ob[k] = (c < 3) ? 1.f : 0.f;
  float emit_f = 0.f, trn_f = 0.f, emit_b = 0.f, trn_b = 0.f;
  int ce_f = 0, ce_b = 0;

  const int myoff = (c == 3) ? 0 : 3 * c;
  const int* plr = &pl[q * PLS];

  WAITV0;                      // path rows + window 0 (both dirs) staged

  int pcur_f = 0;              // last p of previous fwd window
  int pcur_b = plr[255];       // p_255
  int pcf[6], pcb[6];
  PREREAD_F(pcf, 0)
  PREREAD_B(pcb, 0)

  // ================= window 0 (peeled: fwd t==0 special) =================
  {
    PREFETCH_F(1)
    PREFETCH_B(1)
    const float* lxqf = &lxf[0][q * XSTRIDE];
    const float* lxqb = &lxb[0][q * XSTRIDE];
    float eCf[18], eCb[18];
    EBATCH_TO(eCf, lxqf)
    EBATCH_TO(eCb, lxqb)
    float emf[6], trf[6], emb[6], trb[6];
    EMTR_F(emf, trf, lxqf, pcf, 0)
    EMTR_B(emb, trb, lxqb, pcb, pcur_b)
    int pnf[6], pnb[6];
    PREREAD_F(pnf, SPB)
    PREREAD_B(pnb, SPB)
#pragma unroll
    for (int k = 0; k < 3; ++k)
      of[k] = (c < 3) ? fexp(iv[k] + lxqf[myoff + k]) : 0.f;
    BSTEP(0, false);
    FSTEP(1, false);  BSTEP(1, false);
    FSTEP(2, false);  BSTEP(2, false);
    FSTEP(3, false);  BSTEP(3, false);
    FSTEP(4, false);  BSTEP(4, false);
    FSTEP(5, false);  BSTEP(5, false);
#pragma unroll
    for (int kk = 0; kk < 6; ++kk) {
      emit_f += emf[kk]; emit_b += emb[kk]; trn_b += trb[kk];
    }
#pragma unroll
    for (int kk = 1; kk < 6; ++kk) trn_f += trf[kk];   // t==0: no transition
    pcur_f = pcf[5]; pcur_b = pcb[5];
#pragma unroll
    for (int kk = 0; kk < 6; ++kk) { pcf[kk] = pnf[kk]; pcb[kk] = pnb[kk]; }
  }

  // ================= windows 1..20 (dual-chain interleaved) ==============
#pragma unroll 1
  for (int b = 1; b <= 20; ++b) {
    const int tb = b * SPB;
    WAITV0;
    PREFETCH_F(b + 1)
    PREFETCH_B(b + 1)
    const float* lxqf = &lxf[b & 1][q * XSTRIDE];
    const float* lxqb = &lxb[b & 1][q * XSTRIDE];
    float eCf[18], eCb[18];
    EBATCH_TO(eCf, lxqf)
    EBATCH_TO(eCb, lxqb)
    float emf[6], trf[6], emb[6], trb[6];
    EMTR_F(emf, trf, lxqf, pcf, pcur_f)
    EMTR_B(emb, trb, lxqb, pcb, pcur_b)
    int pnf[6], pnb[6];
    PREREAD_F(pnf, tb + SPB)
    PREREAD_B(pnb, tb + SPB)
    FSTEP(0, true);   BSTEP(0, true);
    FSTEP(1, false);  BSTEP(1, false);
    FSTEP(2, false);  BSTEP(2, false);
    FSTEP(3, false);  BSTEP(3, false);
    FSTEP(4, false);  BSTEP(4, false);
    FSTEP(5, false);  BSTEP(5, false);
#pragma unroll
    for (int kk = 0; kk < 6; ++kk) {
      emit_f += emf[kk]; trn_f += trf[kk];
      emit_b += emb[kk]; trn_b += trb[kk];
    }
    pcur_f = pcf[5]; pcur_b = pcb[5];
#pragma unroll
    for (int kk = 0; kk < 6; ++kk) { pcf[kk] = pnf[kk]; pcb[kk] = pnb[kk]; }
  }

  // ================= tail window 21 (2 steps each dir) ===================
  {
    WAITV0;
    const float* lxqf = &lxf[1][q * XSTRIDE];
    const float* lxqb = &lxb[1][q * XSTRIDE];
    float eCf[18], eCb[18];
#pragma unroll
    for (int tt = 0; tt < 2; ++tt)
#pragma unroll
      for (int k = 0; k < 3; ++k)
        eCf[tt * 3 + k] = fexp(lxqf[tt * 9 + myoff + k]);
#pragma unroll
    for (int tt = 4; tt < 6; ++tt)
#pragma unroll
      for (int k = 0; k < 3; ++k)
        eCb[tt * 3 + k] = fexp(lxqb[tt * 9 + myoff + k]);
    float emf[2], trf[2], emb[2], trb[2];
#pragma unroll
    for (int kk = 0; kk < 2; ++kk) {
      emf[kk] = lxqf[kk * 9 + pcf[kk]];
      const int pp_ = kk ? pcf[kk - 1] : pcur_f;
      trf[kk] = ltran[pp_ * 9 + pcf[kk]];
      const int pc_ = kk ? pcb[kk - 1] : pcur_b;
      emb[kk] = lxqb[(5 - kk) * 9 + pc_];
      trb[kk] = ltran[pcb[kk] * 9 + pc_];
    }
    FSTEP(0, true);   BSTEP(0, true);
    FSTEP(1, false);  BSTEP(1, false);
#pragma unroll
    for (int kk = 0; kk < 2; ++kk) {
      emit_f += emf[kk]; trn_f += trf[kk];
      emit_b += emb[kk]; trn_b += trb[kk];
    }
  }

  // ================= in-wave combine =====================================
  float pd = of[0] * ob[0] + of[1] * ob[1] + of[2] * ob[2];  // c==3 -> 0
  pd += QROT(pd, QPX1);        // + xor1 partner
  pd += QROT(pd, QP2);         // + xor2 partner -> full 9-term dot
  const float w10 = emit_f + trn_f + initv[plr[0]];
  const float w21 = emit_b + trn_b;
  const float score =
      (__builtin_amdgcn_logf(pd) + (float)ce_f + (float)ce_b) * LN2f
      - (w10 + w21);
  if (c == 0) out[seq0 + q] = score;
}

extern "C" void kernel_launch(void* const* d_in, const int* in_sizes, int n_in,
                              void* d_out, int out_size, void* d_ws, size_t ws_size,
                              hipStream_t stream) {
  (void)in_sizes; (void)n_in; (void)out_size; (void)d_ws; (void)ws_size;
  const float* xg    = (const float*)d_in[0];
  const int*   path  = (const int*)d_in[1];
  const float* tran  = (const float*)d_in[2];
  const float* initv = (const float*)d_in[3];
  float* out = (float*)d_out;

  crf_fused<<<NBLOCKS, 64, 0, stream>>>(xg, path, tran, initv, out);
}

// Round 12
// 125.326 us; speedup vs baseline: 1.1303x; 1.1303x over previous
//
#include <hip/hip_runtime.h>

// SimpleCRFHead R17: R13 (best: full-wave quad-split split kernels, batched
// path-score, branch-free bodies; crf_half ~37.5us) + tree-split FMA
// accumulation: the 12-deep serial fmaf chain per output state becomes two
// 6-deep half-chains + 1 add (critical path ~48->28cy, +3 adds/step).
// The loop-carried chain o -> DPP -> FMA-chain -> *e -> o is the last
// untouched serialization in the step body. Everything else identical to
// R13. (Summation order change -> absmax eps-level, threshold 14.48.)

#define B_N 8192
#define L_N 256
#define SEQ_STRIDE 2304      // L_N * 9
#define HALF 128
#define SPB 6                // steps per x window
#define XW 54                // floats per seq per window
#define XSTRIDE 55           // odd -> conflict-free LDS banks
#define PLS 129              // path LDS row stride
#define SPW 16               // seqs per wave (full wave: 16 quads)
#define NDIR_BLOCKS (B_N / SPW)   // 512 per direction

#define LOG2E 1.44269504088896340736f
#define LN2f  0.69314718055994530942f

// quad_perm rotate-left-by-r: lane c receives quad-lane (c+r)&3
#define QP1 57    // perm(1,2,3,0)
#define QP2 78    // perm(2,3,0,1)
#define QP3 147   // perm(3,0,1,2)
#define QROT(src, CTRL) \
  __int_as_float(__builtin_amdgcn_mov_dpp(__float_as_int(src), CTRL, 0xf, 0xf, 0))

#define WAITV0 asm volatile("s_waitcnt vmcnt(0)" ::: "memory")

__device__ __forceinline__ void gl_lds4(const void* g, void* l) {
  __builtin_amdgcn_global_load_lds(
      (const __attribute__((address_space(1))) void*)g,
      (__attribute__((address_space(3))) void*)l, 4, 0, 0);
}

__device__ __forceinline__ float fexp(float x) {
  return __builtin_amdgcn_exp2f(x * LOG2E);   // v_exp_f32 = 2^x
}

// ---- straight-line step bodies; 2-way tree accumulation ----
#define FWD_STEP_BODY(KK, DO_RESC)                                          \
  do {                                                                      \
    float g[4][3];                                                          \
    _Pragma("unroll") for (int k = 0; k < 3; ++k) {                         \
      g[0][k] = o[k];                                                       \
      g[1][k] = QROT(o[k], QP1);                                            \
      g[2][k] = QROT(o[k], QP2);                                            \
      g[3][k] = QROT(o[k], QP3);                                            \
    }                                                                       \
    if (DO_RESC) {                                                          \
      float m = g[0][0];                                                    \
      _Pragma("unroll") for (int r = 0; r < 4; ++r)                         \
        _Pragma("unroll") for (int k = 0; k < 3; ++k)                       \
          m = fmaxf(m, g[r][k]);                                            \
      const int ex = (int)((__float_as_uint(m) >> 23) & 0xffu) - 126;       \
      ce += ex;                                                             \
      const float sc = __uint_as_float((unsigned)(127 - ex) << 23);         \
      _Pragma("unroll") for (int r = 0; r < 4; ++r)                         \
        _Pragma("unroll") for (int k = 0; k < 3; ++k)                       \
          g[r][k] *= sc;                                                    \
    }                                                                       \
    float out3[3];                                                          \
    _Pragma("unroll") for (int i = 0; i < 3; ++i) {                         \
      float a1 = Erot[0][0][i] * g[0][0];                                   \
      _Pragma("unroll") for (int r = 0; r < 2; ++r)                         \
        _Pragma("unroll") for (int k = 0; k < 3; ++k)                       \
          if (r + k > 0) a1 = fmaf(Erot[r][k][i], g[r][k], a1);             \
      float a2 = Erot[2][0][i] * g[2][0];                                   \
      _Pragma("unroll") for (int r = 2; r < 4; ++r)                         \
        _Pragma("unroll") for (int k = 0; k < 3; ++k)                       \
          if (r > 2 || k > 0) a2 = fmaf(Erot[r][k][i], g[r][k], a2);        \
      out3[i] = a1 + a2;                                                    \
    }                                                                       \
    _Pragma("unroll") for (int i = 0; i < 3; ++i)                           \
      o[i] = out3[i] * e[(KK) * 3 + i];                                     \
  } while (0)

#define BWD_STEP_BODY(KK, DO_RESC)                                          \
  do {                                                                      \
    const int tt_ = 5 - (KK);                                               \
    float wv[3];                                                            \
    _Pragma("unroll") for (int k = 0; k < 3; ++k)                           \
      wv[k] = e[tt_ * 3 + k] * o[k];                                        \
    float g[4][3];                                                          \
    _Pragma("unroll") for (int k = 0; k < 3; ++k) {                         \
      g[0][k] = wv[k];                                                      \
      g[1][k] = QROT(wv[k], QP1);                                           \
      g[2][k] = QROT(wv[k], QP2);                                           \
      g[3][k] = QROT(wv[k], QP3);                                           \
    }                                                                       \
    if (DO_RESC) {                                                          \
      float m = g[0][0];                                                    \
      _Pragma("unroll") for (int r = 0; r < 4; ++r)                         \
        _Pragma("unroll") for (int k = 0; k < 3; ++k)                       \
          m = fmaxf(m, g[r][k]);                                            \
      const int ex = (int)((__float_as_uint(m) >> 23) & 0xffu) - 126;       \
      ce += ex;                                                             \
      const float sc = __uint_as_float((unsigned)(127 - ex) << 23);         \
      _Pragma("unroll") for (int r = 0; r < 4; ++r)                         \
        _Pragma("unroll") for (int k = 0; k < 3; ++k)                       \
          g[r][k] *= sc;                                                    \
    }                                                                       \
    float out3[3];                                                          \
    _Pragma("unroll") for (int i = 0; i < 3; ++i) {                         \
      float a1 = Erot[0][0][i] * g[0][0];                                   \
      _Pragma("unroll") for (int r = 0; r < 2; ++r)                         \
        _Pragma("unroll") for (int k = 0; k < 3; ++k)                       \
          if (r + k > 0) a1 = fmaf(Erot[r][k][i], g[r][k], a1);             \
      float a2 = Erot[2][0][i] * g[2][0];                                   \
      _Pragma("unroll") for (int r = 2; r < 4; ++r)                         \
        _Pragma("unroll") for (int k = 0; k < 3; ++k)                       \
          if (r > 2 || k > 0) a2 = fmaf(Erot[r][k][i], g[r][k], a2);        \
      out3[i] = a1 + a2;                                                    \
    }                                                                       \
    _Pragma("unroll") for (int i = 0; i < 3; ++i) o[i] = out3[i];           \
  } while (0)

#define PREFETCH_WIN(NB)                                                    \
  if (lane < XW) {                                                          \
    const int fb = fwd ? (NB) * XW : (SEQ_STRIDE - XW * ((NB) + 1));        \
    float* dst = &lx[(NB) & 1][0];                                          \
    _Pragma("unroll") for (int r = 0; r < SPW; ++r)                         \
      gl_lds4(xg + (size_t)(seq0 + r) * SEQ_STRIDE + fb + lane,             \
              dst + r * XSTRIDE);                                           \
  }

#define EBATCH(T0, T1)                                                      \
  _Pragma("unroll") for (int tt = (T0); tt <= (T1); ++tt)                   \
    _Pragma("unroll") for (int k = 0; k < 3; ++k)                           \
      e[tt * 3 + k] = fexp(lxq[tt * 9 + myoff + k]);

#define EMTR_FWD(N)                                                         \
  _Pragma("unroll") for (int kk = 0; kk < (N); ++kk) {                      \
    em[kk] = lxq[kk * 9 + pc6[kk]];                                         \
    const int pp = kk ? pc6[kk - 1] : pcur;                                 \
    tr[kk] = ltran[pp * 9 + pc6[kk]];                                       \
  }

#define EMTR_BWD(N)                                                         \
  _Pragma("unroll") for (int kk = 0; kk < (N); ++kk) {                      \
    const int pc = kk ? pc6[kk - 1] : pcur;                                 \
    em[kk] = lxq[(5 - kk) * 9 + pc];                                        \
    tr[kk] = ltran[pc6[kk] * 9 + pc];                                       \
  }

#define PREREAD_PN(TBN)                                                     \
  if (fwd) {                                                                \
    _Pragma("unroll") for (int kk = 0; kk < SPB; ++kk) {                    \
      int t = (TBN) + kk; if (t > HALF - 1) t = HALF - 1;                   \
      pn6[kk] = plr[t];                                                     \
    }                                                                       \
  } else {                                                                  \
    _Pragma("unroll") for (int kk = 0; kk < SPB; ++kk) {                    \
      int idx = 127 - (TBN) - kk; if (idx < 0) idx = 0;                     \
      pn6[kk] = plr[idx];                                                   \
    }                                                                       \
  }

__global__ __launch_bounds__(64, 1) void crf_half(
    const float* __restrict__ xg, const int* __restrict__ path,
    const float* __restrict__ tran, const float* __restrict__ initv,
    float* __restrict__ ws)
{
  __shared__ float lx[2][SPW * XSTRIDE];  // 7040 B
  __shared__ int   pl[SPW * PLS];         // 8256 B
  __shared__ int   pl255[SPW];
  __shared__ float ltran[81];             // ~15.7 KB -> 4 blocks/CU

  const int lane = threadIdx.x;
  const int c = lane & 3;                 // quad slot (state group)
  const int q = lane >> 2;                // seq slot (0..15, all active)
  const bool fwd = (int)blockIdx.x < NDIR_BLOCKS;
  const int seq0 = (fwd ? blockIdx.x : blockIdx.x - NDIR_BLOCKS) * SPW;

  for (int i = lane; i < 81; i += 64) ltran[i] = tran[i];

  // ---- stage path rows + x window 0 (coalesced gl_lds)
  {
    const int t0 = fwd ? 0 : 127;
#pragma unroll
    for (int r = 0; r < SPW; ++r) {
      const int* g = path + (size_t)(seq0 + r) * L_N + t0 + lane;
      gl_lds4(g,      &pl[r * PLS]);
      gl_lds4(g + 64, &pl[r * PLS + 64]);
    }
  }
  if (!fwd && lane < SPW)
    pl255[lane] = path[(size_t)(seq0 + lane) * L_N + 255];
  if (lane < XW) {
    const int fb = fwd ? 0 : (SEQ_STRIDE - XW);
#pragma unroll
    for (int r = 0; r < SPW; ++r)
      gl_lds4(xg + (size_t)(seq0 + r) * SEQ_STRIDE + fb + lane,
              &lx[0][r * XSTRIDE]);
  }

  // ---- rotation-ordered transition coefficients (prologue only)
  float Erot[4][3][3];
#pragma unroll
  for (int r = 0; r < 4; ++r)
#pragma unroll
    for (int k = 0; k < 3; ++k)
#pragma unroll
      for (int i = 0; i < 3; ++i) {
        const int ig = 3 * c + i;
        const int jg = 3 * ((c + r) & 3) + k;
        float v = 0.f;
        if (ig < 9 && jg < 9)
          v = fexp(fwd ? tran[jg * 9 + ig] : tran[ig * 9 + jg]);
        Erot[r][k][i] = v;
      }

  float iv[3];
#pragma unroll
  for (int k = 0; k < 3; ++k) {
    iv[k] = (fwd && c < 3) ? initv[3 * c + k] : 0.f;
    asm volatile("" :: "v"(iv[k]));       // pin materialization to prologue
  }

  float o[3];
  float emit = 0.f, trn = 0.f;
  int ce = 0, pcur = 0;
  if (!fwd) {
#pragma unroll
    for (int k = 0; k < 3; ++k) o[k] = (c < 3) ? 1.f : 0.f;
  }

  const int myoff = (c == 3) ? 0 : 3 * c;
  const int* plr = &pl[q * PLS];

  WAITV0;                     // path rows + window 0 staged
  if (!fwd) pcur = pl255[q];  // p_255

  int pc6[SPB];
  if (fwd) {
#pragma unroll
    for (int kk = 0; kk < SPB; ++kk) pc6[kk] = plr[kk];
  } else {
#pragma unroll
    for (int kk = 0; kk < SPB; ++kk) pc6[kk] = plr[127 - kk];
  }

  // ================= window 0 (fwd: t==0 special) =================
  {
    PREFETCH_WIN(1)
    const float* lxq = &lx[0][q * XSTRIDE];
    float e[SPB * 3];
    EBATCH(0, 5)
    float em[SPB], tr[SPB];
    int pn6[SPB];
    if (fwd) { EMTR_FWD(6) } else { EMTR_BWD(6) }
    PREREAD_PN(SPB)
    if (fwd) {
#pragma unroll
      for (int k = 0; k < 3; ++k)
        o[k] = (c < 3) ? fexp(iv[k] + lxq[myoff + k]) : 0.f;
      FWD_STEP_BODY(1, false);
      FWD_STEP_BODY(2, false);
      FWD_STEP_BODY(3, false);
      FWD_STEP_BODY(4, false);
      FWD_STEP_BODY(5, false);
#pragma unroll
      for (int kk = 0; kk < 6; ++kk) emit += em[kk];
#pragma unroll
      for (int kk = 1; kk < 6; ++kk) trn += tr[kk];  // t==0: no transition
    } else {
      BWD_STEP_BODY(0, false);
      BWD_STEP_BODY(1, false);
      BWD_STEP_BODY(2, false);
      BWD_STEP_BODY(3, false);
      BWD_STEP_BODY(4, false);
      BWD_STEP_BODY(5, false);
#pragma unroll
      for (int kk = 0; kk < 6; ++kk) { emit += em[kk]; trn += tr[kk]; }
    }
    pcur = pc6[SPB - 1];
#pragma unroll
    for (int kk = 0; kk < SPB; ++kk) pc6[kk] = pn6[kk];
  }

  // ================= windows 1..20 (branch-free bodies) =================
#pragma unroll 1
  for (int b = 1; b <= 20; ++b) {
    const int tb = b * SPB;
    WAITV0;                   // window b staged
    PREFETCH_WIN(b + 1)
    const float* lxq = &lx[b & 1][q * XSTRIDE];
    float e[SPB * 3];
    EBATCH(0, 5)
    float em[SPB], tr[SPB];
    int pn6[SPB];
    if (fwd) { EMTR_FWD(6) } else { EMTR_BWD(6) }
    PREREAD_PN(tb + SPB)
    if (fwd) {
      FWD_STEP_BODY(0, true);   // rescale once per window
      FWD_STEP_BODY(1, false);
      FWD_STEP_BODY(2, false);
      FWD_STEP_BODY(3, false);
      FWD_STEP_BODY(4, false);
      FWD_STEP_BODY(5, false);
    } else {
      BWD_STEP_BODY(0, true);
      BWD_STEP_BODY(1, false);
      BWD_STEP_BODY(2, false);
      BWD_STEP_BODY(3, false);
      BWD_STEP_BODY(4, false);
      BWD_STEP_BODY(5, false);
    }
#pragma unroll
    for (int kk = 0; kk < 6; ++kk) { emit += em[kk]; trn += tr[kk]; }
    pcur = pc6[SPB - 1];
#pragma unroll
    for (int kk = 0; kk < SPB; ++kk) pc6[kk] = pn6[kk];
  }

  // ================= tail window 21 (2 steps: t=126,127) =================
  {
    WAITV0;                   // window 21 staged
    const float* lxq = &lx[1][q * XSTRIDE];   // 21 & 1
    float e[SPB * 3];
    float em[SPB], tr[SPB];
    if (fwd) {
      EBATCH(0, 1)            // tt=0,1 -> t=126,127
      EMTR_FWD(2)
      FWD_STEP_BODY(0, true);
      FWD_STEP_BODY(1, false);
    } else {
      EBATCH(4, 5)            // tt=5,4 -> t=129,128
      EMTR_BWD(2)
      BWD_STEP_BODY(0, true);
      BWD_STEP_BODY(1, false);
    }
#pragma unroll
    for (int kk = 0; kk < 2; ++kk) { emit += em[kk]; trn += tr[kk]; }
  }

  // ---- write partials (field-major)
  const int sq = seq0 + q;
  float* wp = ws + sq;
  if (fwd) {
    if (c < 3) {
#pragma unroll
      for (int k = 0; k < 3; ++k) wp[(3 * c + k) * B_N] = o[k];
    } else {
      wp[9 * B_N] = (float)ce;
      wp[10 * B_N] = emit + trn + initv[plr[0]];
    }
  } else {
    if (c < 3) {
#pragma unroll
      for (int k = 0; k < 3; ++k) wp[(11 + 3 * c + k) * B_N] = o[k];
    } else {
      wp[20 * B_N] = (float)ce;
      wp[21 * B_N] = emit + trn;
    }
  }
}

__global__ __launch_bounds__(256) void crf_combine(
    const float* __restrict__ ws, float* __restrict__ out)
{
  const int s = blockIdx.x * 256 + threadIdx.x;
  float dot = 0.f;
#pragma unroll
  for (int i = 0; i < 9; ++i)
    dot = fmaf(ws[i * B_N + s], ws[(11 + i) * B_N + s], dot);
  const float score =
      (__builtin_amdgcn_logf(dot) + ws[9 * B_N + s] + ws[20 * B_N + s]) * LN2f;
  out[s] = score - (ws[10 * B_N + s] + ws[21 * B_N + s]);
}

extern "C" void kernel_launch(void* const* d_in, const int* in_sizes, int n_in,
                              void* d_out, int out_size, void* d_ws, size_t ws_size,
                              hipStream_t stream) {
  (void)in_sizes; (void)n_in; (void)out_size; (void)ws_size;
  const float* xg    = (const float*)d_in[0];
  const int*   path  = (const int*)d_in[1];
  const float* tran  = (const float*)d_in[2];
  const float* initv = (const float*)d_in[3];
  float* ws  = (float*)d_ws;    // 22*8192*4 = 721 KB
  float* out = (float*)d_out;

  crf_half<<<2 * NDIR_BLOCKS, 64, 0, stream>>>(xg, path, tran, initv, ws);
  crf_combine<<<B_N / 256, 256, 0, stream>>>(ws, out);
}